// Round 7
// baseline (2371.925 us; speedup 1.0000x reference)
//
#include <hip/hip_runtime.h>
#include <hip/hip_bf16.h>
#include <cstdint>
#include <cstddef>

typedef __bf16 bf16_t;
typedef bf16_t bf16x8 __attribute__((ext_vector_type(8)));
typedef bf16_t bf16x4 __attribute__((ext_vector_type(4)));
typedef float  f32x4  __attribute__((ext_vector_type(4)));
typedef unsigned short u16x8 __attribute__((ext_vector_type(8)));

#define TT    64
#define T_CTX 24
#define HOR   40
#define SA    264     // LDS row stride (K=256 + 8 pad): 528B, 16B-aligned
#define NTH   512     // 8 waves
#define EWS   132     // s_ew node stride (floats)

#define MFMA __builtin_amdgcn_mfma_f32_16x16x32_bf16

// ---- ws layout (bf16-element offsets; flag int at elem 0) ----
#define O_PKE   16                      // enc stream: 8 waves x 64 frags x 512
#define O_PKD   (O_PKE + 262144)        // dec stream: 8 x 72 x 512
#define O_PKX   (O_PKD + 294912)        // enc-term stream: 8 x 32 x 512
#define O_BIAS  (O_PKX + 131072)        // 4 x 512
#define O_HEADP (O_BIAS + 2048)         // h2in_b1|h2in_W2|h2out_b1|h2out_W2
#define O_WINE  (O_HEADP + 512)         // enc_W_in rows padded to 12
#define O_WINN  (O_WINE + 1536)
#define O_B2    (O_WINN + 1536)

struct Ptrs { const void* q[29]; };

__device__ __forceinline__ float sigm(float x) {
  return __builtin_amdgcn_rcpf(1.f + __expf(-x));
}
__device__ __forceinline__ float tanh_(float x) {
  return 1.f - 2.f * __builtin_amdgcn_rcpf(1.f + __expf(2.f * x));
}
__device__ __forceinline__ unsigned pk2(float a, float b) {
  unsigned ua = __float_as_uint(a), ub = __float_as_uint(b);
  ua = (ua + 0x7fffu + ((ua >> 16) & 1u)) >> 16;
  ub = (ub + 0x7fffu + ((ub >> 16) & 1u)) >> 16;
  return ua | (ub << 16);
}
__device__ __forceinline__ float uplo(unsigned p){ return __uint_as_float(p << 16); }
__device__ __forceinline__ float uphi(unsigned p){ return __uint_as_float(p & 0xffff0000u); }

// ================= dtype detector (unchanged, validated r2) =================
__global__ void detect_kernel(const unsigned short* __restrict__ wsrc, int* __restrict__ flag)
{
  int tid = threadIdx.x;
  int wild = 0;
  for (int i = tid; i < 256; i += 64) {
    unsigned short b = wsrc[i];
    float v  = __uint_as_float(((unsigned)b) << 16);
    float av = fabsf(v);
    unsigned e = (b >> 7) & 0xff;
    if (av > 1000.f || e == 0xff || (((b & 0x7fff) != 0) && av < 1e-9f)) wild++;
  }
  for (int off = 32; off; off >>= 1) wild += __shfl_down(wild, off, 64);
  if (tid == 0) flag[0] = (wild > 16) ? 1 : 0;
}

// ================= prep: pack weights into per-wave consumption-order streams =================
__global__ void prep_kernel(Ptrs P, bf16_t* __restrict__ wb, const int* __restrict__ flag)
{
  const bool f32 = (flag[0] != 0);
  const int gtid = blockIdx.x * blockDim.x + threadIdx.x;
  const int gsz  = gridDim.x * blockDim.x;
  auto rd = [&](const void* src, int i) -> float {
    return f32 ? ((const float*)src)[i] : (float)((const bf16_t*)src)[i];
  };

  // E stream: [w][seg(E0|E1)][kt][g] frags
  for (int i = gtid; i < 262144; i += gsz) {
    int w = i >> 15, r = i & 32767, f = r >> 9, e = r & 511;
    int ln = e >> 3, j = e & 7;
    int seg = f >> 5, fk = f & 31, kt = fk >> 2, g = fk & 3;
    int row = g * 128 + w * 16 + (ln & 15);
    int col = kt * 32 + ((ln >> 4) << 3) + j;
    float v;
    if (seg == 0) v = (col < 128) ? rd(P.q[4], row * 128 + col) : rd(P.q[5], row * 128 + col - 128);
    else          v = (col < 128) ? rd(P.q[8], row * 128 + col) : rd(P.q[9], row * 128 + col - 128);
    wb[O_PKE + i] = (bf16_t)v;
  }
  // D stream: [w][D0(32)|D1(32)|H(8)]
  for (int i = gtid; i < 294912; i += gsz) {
    int w = i / 36864, r = i - w * 36864, f = r >> 9, e = r & 511;
    int ln = e >> 3, j = e & 7;
    int colk = ((ln >> 4) << 3) + j;
    float v;
    if (f < 64) {
      int seg = f >> 5, fk = f & 31, kt = fk >> 2, g = fk & 3;
      int row = g * 128 + w * 16 + (ln & 15);
      int col = kt * 32 + colk;
      if (seg == 0) v = (col < 128) ? rd(P.q[13], row * 256 + col) : rd(P.q[14], row * 128 + col - 128);
      else          v = (col < 128) ? rd(P.q[17], row * 128 + col) : rd(P.q[18], row * 128 + col - 128);
    } else {
      int f2 = f - 64, h = f2 >> 2, kt = f2 & 3;
      int row = w * 16 + (ln & 15);
      int col = kt * 32 + colk;
      v = rd(h ? P.q[25] : P.q[21], row * 128 + col);
    }
    wb[O_PKD + i] = (bf16_t)v;
  }
  // X stream: inWih[:, 128:256]
  for (int i = gtid; i < 131072; i += gsz) {
    int w = i >> 14, r = i & 16383, f = r >> 9, e = r & 511;
    int ln = e >> 3, j = e & 7;
    int kt = f >> 2, g = f & 3;
    int row = g * 128 + w * 16 + (ln & 15);
    int col = kt * 32 + ((ln >> 4) << 3) + j;
    wb[O_PKX + i] = (bf16_t)rd(P.q[13], row * 256 + 128 + col);
  }
  // biases / head params / input-proj weights
  for (int i = gtid; i < 512; i += gsz) {
    wb[O_BIAS + i]        = (bf16_t)(rd(P.q[6],  i) + rd(P.q[7],  i));
    wb[O_BIAS + 512 + i]  = (bf16_t)(rd(P.q[10], i) + rd(P.q[11], i));
    wb[O_BIAS + 1024 + i] = (bf16_t)(rd(P.q[15], i) + rd(P.q[16], i));
    wb[O_BIAS + 1536 + i] = (bf16_t)(rd(P.q[19], i) + rd(P.q[20], i));
  }
  for (int i = gtid; i < 128; i += gsz) {
    wb[O_HEADP + i]       = (bf16_t)rd(P.q[22], i);
    wb[O_HEADP + 128 + i] = (bf16_t)rd(P.q[23], i);
    wb[O_HEADP + 256 + i] = (bf16_t)rd(P.q[26], i);
    wb[O_HEADP + 384 + i] = (bf16_t)rd(P.q[27], i);
  }
  for (int i = gtid; i < 1536; i += gsz) {
    int cc = i / 12, j = i % 12;
    wb[O_WINE + i] = (j < 10) ? (bf16_t)rd(P.q[3],  cc * 10 + j) : (bf16_t)0.f;
    wb[O_WINN + i] = (j < 10) ? (bf16_t)rd(P.q[12], cc * 10 + j) : (bf16_t)0.f;
  }
  if (gtid == 0) {
    wb[O_B2]     = (bf16_t)rd(P.q[24], 0);
    wb[O_B2 + 1] = (bf16_t)rd(P.q[28], 0);
  }
}

// ================= main-kernel building blocks =================
struct PreB { bf16x8 b[3][4]; };   // first 3 kt (12 frags) of a stream

__device__ __forceinline__ PreB preB(const bf16_t* __restrict__ pl) {
  PreB r;
#pragma unroll
  for (int p = 0; p < 3; ++p)
#pragma unroll
    for (int g = 0; g < 4; ++g)
      r.b[p][g] = *(const bf16x8*)(pl + (p * 4 + g) * 512);
  return r;
}

// acc[g][mt] += A[64, 32*NKT](LDS, stride SA) @ Wstream^T.
// Ring depth 4; first 3 kt arrive via cross-barrier bundle (pre). bw[3] issued
// at kt=0 (cover 3 kt); in-loop refills have 4-kt cover (~600cy). The NEXT
// phase's 3-kt bundle (pf) is issued spread over kt=1..3 so its latency hides
// under the rest of this gemm + cell_up + barrier.
template<int NKT>
__device__ __forceinline__ void gemm_pk(f32x4 (&acc)[4][4], const bf16_t* __restrict__ As,
                                        const bf16_t* __restrict__ pl, const PreB& pre,
                                        const bf16_t* __restrict__ plpf, PreB* __restrict__ pf,
                                        int l, int q)
{
  bf16x8 bw[4][4];
#pragma unroll
  for (int p = 0; p < 3; ++p)
#pragma unroll
    for (int g = 0; g < 4; ++g) bw[p][g] = pre.b[p][g];
#pragma unroll
  for (int kt = 0; kt < NKT; ++kt) {
    if (kt == 0 && NKT > 3) {
#pragma unroll
      for (int g = 0; g < 4; ++g)
        bw[3][g] = *(const bf16x8*)(pl + (12 + g) * 512);
    }
    if (kt >= 1 && kt <= 3) {
#pragma unroll
      for (int g = 0; g < 4; ++g)
        pf->b[kt - 1][g] = *(const bf16x8*)(plpf + ((kt - 1) * 4 + g) * 512);
    }
    const bf16_t* Ar = As + l * SA + kt * 32 + q * 8;
    bf16x8 a0 = *(const bf16x8*)(Ar);
    bf16x8 a1 = *(const bf16x8*)(Ar + 16 * SA);
#pragma unroll
    for (int g = 0; g < 4; ++g) acc[g][0] = MFMA(a0, bw[kt % 4][g], acc[g][0], 0, 0, 0);
    a0 = *(const bf16x8*)(Ar + 32 * SA);
#pragma unroll
    for (int g = 0; g < 4; ++g) acc[g][1] = MFMA(a1, bw[kt % 4][g], acc[g][1], 0, 0, 0);
    a1 = *(const bf16x8*)(Ar + 48 * SA);
#pragma unroll
    for (int g = 0; g < 4; ++g) acc[g][2] = MFMA(a0, bw[kt % 4][g], acc[g][2], 0, 0, 0);
#pragma unroll
    for (int g = 0; g < 4; ++g) acc[g][3] = MFMA(a1, bw[kt % 4][g], acc[g][3], 0, 0, 0);
    // refill AFTER use: slot kt%4 just freed; data for kt+4 (lookahead 4)
    if (kt + 4 < NKT) {
#pragma unroll
      for (int g = 0; g < 4; ++g)
        bw[kt % 4][g] = *(const bf16x8*)(pl + ((kt + 4) * 4 + g) * 512);
    }
  }
}

// i,f,g,o for unit jc all in-lane (C layout: node=q*4+r within mt, unit=l). c in VGPRs.
template<bool DUAL>
__device__ __forceinline__ void cell_up(f32x4 (&acc)[4][4], float (&c)[16],
                                        bf16_t* __restrict__ shb, bf16_t* __restrict__ sha,
                                        const bf16_t* __restrict__ bias,
                                        int wid, int l, int q)
{
  const int jc = wid * 16 + l;
  const float bi  = (float)bias[jc];
  const float bf_ = (float)bias[128 + jc];
  const float bg  = (float)bias[256 + jc];
  const float bo  = (float)bias[384 + jc];
#pragma unroll
  for (int mt = 0; mt < 4; ++mt) {
#pragma unroll
    for (int r = 0; r < 4; ++r) {
      float gi = acc[0][mt][r] + bi;
      float gf = acc[1][mt][r] + bf_;
      float gg = acc[2][mt][r] + bg;
      float go = acc[3][mt][r] + bo;
      float cn = sigm(gf) * c[mt * 4 + r] + sigm(gi) * tanh_(gg);
      float hh = sigm(go) * tanh_(cn);
      c[mt * 4 + r] = cn;
      const int row = mt * 16 + q * 4 + r;
      shb[row * SA + jc] = (bf16_t)hh;
      if (DUAL) sha[row * SA + jc] = (bf16_t)hh;
    }
  }
}

__device__ __forceinline__ void proj16(const float* v, const bf16_t* __restrict__ wbase,
                                       bf16_t* __restrict__ sx, int nd, int sub)
{
  bf16x8 o0, o1;
#pragma unroll
  for (int cc = 0; cc < 16; ++cc) {
    const bf16_t* wr = wbase + (sub * 16 + cc) * 12;
    bf16x4 w0 = *(const bf16x4*)(wr);
    bf16x4 w1 = *(const bf16x4*)(wr + 4);
    bf16x4 w2 = *(const bf16x4*)(wr + 8);
    float a = v[0] * (float)w0[0] + v[1] * (float)w0[1] + v[2] * (float)w0[2] + v[3] * (float)w0[3]
            + v[4] * (float)w1[0] + v[5] * (float)w1[1] + v[6] * (float)w1[2] + v[7] * (float)w1[3]
            + v[8] * (float)w2[0] + v[9] * (float)w2[1];
    if (cc < 8) o0[cc] = (bf16_t)a; else o1[cc - 8] = (bf16_t)a;
  }
  *(bf16x8*)(sx + nd * SA + sub * 16)     = o0;
  *(bf16x8*)(sx + nd * SA + sub * 16 + 8) = o1;
}

// ================= persistent LSTM kernel =================
// __launch_bounds__(NTH, 1): LDS (122.6KB) limits to 1 block/CU anyway; the
// previous (NTH, 2) told the compiler to fit 2 blocks/CU -> 4 waves/SIMD ->
// VGPR cap 128 -> R6's ring-4 state spilled to scratch (WRITE_SIZE 2x).
// With 1: cap is 256 (2 waves/SIMD, the workgroup's own co-residency bound).
template<typename T>
__global__ __launch_bounds__(NTH, 1) void lstm_persist(
    const T* __restrict__ x, const T* __restrict__ coords, const T* __restrict__ env,
    const bf16_t* __restrict__ w, const int* __restrict__ flag, T* __restrict__ out)
{
  const bool want_f32 = (sizeof(T) == 4);
  if ((flag[0] != 0) != want_f32) return;

  __shared__ __align__(16) bf16_t bufA[64 * SA];   // [inp | h0]
  __shared__ __align__(16) bf16_t bufB[64 * SA];   // [h0 | h1]
  __shared__ __align__(16) bf16_t s_win[2 * 128 * 12];
  __shared__ __align__(16) bf16_t s_bias[4 * 512];
  __shared__ float s_red[128];
  __shared__ float s_xc[64];
  __shared__ __align__(16) float s_ew[64 * EWS];   // 16-step window: [node][e0..6|x][16]
  __shared__ float s_out[64 * HOR];                // [node][s]

  const int tid  = threadIdx.x;
  const int wid  = tid >> 6;
  const int lane = tid & 63;
  const int l    = tid & 15;
  const int q    = (tid & 63) >> 4;
  const int node0 = blockIdx.x * 64;
  const int nd  = tid >> 3;
  const int sub = tid & 7;
  const int nd_e = tid / 7;            // env row indices (valid tid<448)
  const int e_e  = tid - nd_e * 7;

  const bf16_t* plE0 = w + O_PKE + wid * 32768 + lane * 8;
  const bf16_t* plE1 = plE0 + 16384;
  const bf16_t* plD0 = w + O_PKD + wid * 36864 + lane * 8;
  const bf16_t* plD1 = plD0 + 16384;
  const bf16_t* plH  = plD0 + 32768;
  const bf16_t* plX  = w + O_PKX + wid * 16384 + lane * 8;

  // env/x 16-step window loader (NT: single-touch per block)
  auto load_ew = [&](int t0) {
    float* dst = (tid < 448) ? &s_ew[nd_e * EWS + e_e * 16]
                             : &s_ew[(tid - 448) * EWS + 112];
    const T* src = (tid < 448) ? env + ((size_t)(node0 + nd_e) * 7 + e_e) * TT + t0
                               : x + (size_t)(node0 + tid - 448) * TT + t0;
    if constexpr (sizeof(T) == 4) {
#pragma unroll
      for (int u = 0; u < 4; ++u) {
        f32x4 vv = __builtin_nontemporal_load((const f32x4*)src + u);
        *((f32x4*)dst + u) = vv;
      }
    } else {
#pragma unroll
      for (int u = 0; u < 2; ++u) {
        u16x8 vv = __builtin_nontemporal_load((const u16x8*)src + u);
#pragma unroll
        for (int k = 0; k < 8; ++k)
          dst[u * 8 + k] = __uint_as_float(((unsigned)vv[k]) << 16);
      }
    }
  };

  for (int i = tid; i < 2048; i += NTH) s_bias[i] = w[O_BIAS + i];
  for (int i = tid; i < 3072; i += NTH) s_win[i]  = w[O_WINE + i];
  for (int i = tid; i < 64 * SA; i += NTH) { bufA[i] = (bf16_t)0.f; bufB[i] = (bf16_t)0.f; }
  load_ew(0);

  const float cx = (float)coords[(size_t)(node0 + nd) * 2 + 0];
  const float cy = (float)coords[(size_t)(node0 + nd) * 2 + 1];

  float c0[16], c1[16];
#pragma unroll
  for (int i = 0; i < 16; ++i) { c0[i] = 0.f; c1[i] = 0.f; }

  PreB pA = preB(plE0);
  PreB pD;
  __syncthreads();

  // ================= encoder =================
#pragma unroll 1
  for (int t = 0; t < T_CTX; ++t) {
    if (t == 16) { __syncthreads(); load_ew(16); __syncthreads(); }
    const int tw = t & 15;
    float v[10];
    v[0] = s_ew[nd * EWS + 112 + tw];
    v[1] = cx; v[2] = cy;
#pragma unroll
    for (int e = 0; e < 7; ++e) v[3 + e] = s_ew[nd * EWS + e * 16 + tw];
    proj16(v, s_win, bufA, nd, sub);
    __syncthreads();                           // E1: bufA ready

    f32x4 acc[4][4];
#pragma unroll
    for (int g = 0; g < 4; ++g)
#pragma unroll
      for (int mt = 0; mt < 4; ++mt) acc[g][mt] = f32x4{0.f, 0.f, 0.f, 0.f};
    PreB pC;
    gemm_pk<8>(acc, bufA, plE0, pA, plE1, &pC, l, q);
    __syncthreads();                           // E2: bufA consumed
    cell_up<true>(acc, c0, bufB, bufA + 128, s_bias, wid, l, q);
    __syncthreads();                           // E3: bufB[0:128] ready

#pragma unroll
    for (int g = 0; g < 4; ++g)
#pragma unroll
      for (int mt = 0; mt < 4; ++mt) acc[g][mt] = f32x4{0.f, 0.f, 0.f, 0.f};
    gemm_pk<8>(acc, bufB, plE1, pC, (t < T_CTX - 1) ? plE0 : plX, &pA, l, q);
    __syncthreads();                           // E4: bufB consumed
    cell_up<false>(acc, c1, bufB + 128, nullptr, s_bias + 512, wid, l, q);
  }
  __syncthreads();                             // enc-final h1 visible

  // ---- enc_state @ inWih[:,128:256]^T once, cached as bf16 (hi) ----
  uint2 geh[4][4];
  {
    f32x4 acc[4][4];
#pragma unroll
    for (int g = 0; g < 4; ++g)
#pragma unroll
      for (int mt = 0; mt < 4; ++mt) acc[g][mt] = f32x4{0.f, 0.f, 0.f, 0.f};
    gemm_pk<4>(acc, bufB + 128, plX, pA, plD0, &pD, l, q);   // prefetch pD here
#pragma unroll
    for (int g = 0; g < 4; ++g)
#pragma unroll
      for (int mt = 0; mt < 4; ++mt)
        geh[g][mt] = uint2{pk2(acc[g][mt][0], acc[g][mt][1]),
                           pk2(acc[g][mt][2], acc[g][mt][3])};
  }
  // x[:, T_CTX-1]: t=23 lives in resident window 1 (t16..31)
  if (tid < 64) s_xc[tid] = s_ew[tid * EWS + 112 + 7];
  const float b2i = (float)w[O_B2];
  const float b2o = (float)w[O_B2 + 1];
  const float b1i = (float)w[O_HEADP + wid * 16 + l];
  const float w2i = (float)w[O_HEADP + 128 + wid * 16 + l];
  const float b1o = (float)w[O_HEADP + 256 + wid * 16 + l];
  const float w2o = (float)w[O_HEADP + 384 + wid * 16 + l];
  __syncthreads();                             // s_xc ready

  // ================= decoder =================
#pragma unroll 1
  for (int s = 0; s < HOR; ++s) {
    const int t = T_CTX + s;
    if ((t & 15) == 0) { load_ew(t); __syncthreads(); }
    const int tw = t & 15;
    float v[10];
    v[0] = s_xc[nd];
    v[1] = cx; v[2] = cy;
#pragma unroll
    for (int e = 0; e < 7; ++e) v[3 + e] = s_ew[nd * EWS + e * 16 + tw];
    proj16(v, s_win + 1536, bufA, nd, sub);
    __syncthreads();                           // S1: bufA ready

    f32x4 acc[4][4];
#pragma unroll
    for (int g = 0; g < 4; ++g)
#pragma unroll
      for (int mt = 0; mt < 4; ++mt)
        acc[g][mt] = f32x4{uplo(geh[g][mt].x), uphi(geh[g][mt].x),
                           uplo(geh[g][mt].y), uphi(geh[g][mt].y)};
    PreB pC;
    gemm_pk<8>(acc, bufA, plD0, pD, plD1, &pC, l, q);
    __syncthreads();                           // S2: bufA consumed
    cell_up<true>(acc, c0, bufB, bufA + 128, s_bias + 1024, wid, l, q);
    __syncthreads();                           // S3: bufB[0:128] ready

#pragma unroll
    for (int g = 0; g < 4; ++g)
#pragma unroll
      for (int mt = 0; mt < 4; ++mt) acc[g][mt] = f32x4{0.f, 0.f, 0.f, 0.f};
    gemm_pk<8>(acc, bufB, plD1, pC, plD0, &pD, l, q);        // prefetch next-step pD
    bf16x8 hb[8];
#pragma unroll
    for (int f = 0; f < 8; ++f) hb[f] = *(const bf16x8*)(plH + f * 512);
    __syncthreads();                           // S4: bufB consumed
    cell_up<false>(acc, c1, bufB + 128, nullptr, s_bias + 1536, wid, l, q);
    if (tid < 128) s_red[tid] = 0.f;
    __syncthreads();                           // S5: h1 + s_red ready

    // ---- heads ----
    f32x4 hacc[2][4];
#pragma unroll
    for (int hd = 0; hd < 2; ++hd)
#pragma unroll
      for (int mt = 0; mt < 4; ++mt) hacc[hd][mt] = f32x4{0.f, 0.f, 0.f, 0.f};
#pragma unroll
    for (int kt = 0; kt < 4; ++kt) {
      bf16x8 a[4];
#pragma unroll
      for (int mt = 0; mt < 4; ++mt)
        a[mt] = *(const bf16x8*)(bufB + 128 + (mt * 16 + l) * SA + kt * 32 + q * 8);
#pragma unroll
      for (int mt = 0; mt < 4; ++mt) {
        hacc[0][mt] = MFMA(a[mt], hb[kt],     hacc[0][mt], 0, 0, 0);
        hacc[1][mt] = MFMA(a[mt], hb[4 + kt], hacc[1][mt], 0, 0, 0);
      }
    }
#pragma unroll
    for (int hd = 0; hd < 2; ++hd) {
      const float b1v = hd ? b1o : b1i;
      const float w2v = hd ? w2o : w2i;
#pragma unroll
      for (int mt = 0; mt < 4; ++mt)
#pragma unroll
        for (int r = 0; r < 4; ++r) {
          float val = fmaxf(hacc[hd][mt][r] + b1v, 0.f) * w2v;
          val += __shfl_xor(val, 1, 64);
          val += __shfl_xor(val, 2, 64);
          val += __shfl_xor(val, 4, 64);
          val += __shfl_xor(val, 8, 64);
          if (l == 0) atomicAdd(&s_red[hd * 64 + mt * 16 + q * 4 + r], val);
        }
    }
    __syncthreads();                           // S6: s_red complete
    if (tid < 64) {
      float xc = s_xc[tid];
      float si = sigm(s_red[tid] + b2i);
      float so = sigm(s_red[64 + tid] + b2o);
      float xn = xc + si - so * xc;
      s_xc[tid] = xn;
      s_out[tid * HOR + s] = xn;
    }
    __syncthreads();                           // S7: s_xc stable
  }

  // dump block outputs once, coalesced
  for (int i = tid; i < 64 * HOR; i += NTH)
    out[(size_t)node0 * HOR + i] = (T)s_out[i];
}

extern "C" void kernel_launch(void* const* d_in, const int* in_sizes, int n_in,
                              void* d_out, int out_size, void* d_ws, size_t ws_size,
                              hipStream_t stream) {
  (void)in_sizes; (void)n_in; (void)out_size; (void)ws_size;
  Ptrs P;
  for (int i = 0; i < 29; ++i) P.q[i] = d_in[i];
  int*    flag = (int*)d_ws;
  bf16_t* w    = (bf16_t*)d_ws;

  detect_kernel<<<1, 64, 0, stream>>>((const unsigned short*)d_in[4], flag);
  prep_kernel<<<256, 256, 0, stream>>>(P, w, flag);
  lstm_persist<float><<<256, NTH, 0, stream>>>(
      (const float*)d_in[0], (const float*)d_in[1], (const float*)d_in[2],
      w, flag, (float*)d_out);
  lstm_persist<bf16_t><<<256, NTH, 0, stream>>>(
      (const bf16_t*)d_in[0], (const bf16_t*)d_in[1], (const bf16_t*)d_in[2],
      w, flag, (bf16_t*)d_out);
}

// Round 8
// 1928.184 us; speedup vs baseline: 1.2301x; 1.2301x over previous
//
#include <hip/hip_runtime.h>
#include <hip/hip_bf16.h>
#include <cstdint>
#include <cstddef>

typedef __bf16 bf16_t;
typedef bf16_t bf16x8 __attribute__((ext_vector_type(8)));
typedef bf16_t bf16x4 __attribute__((ext_vector_type(4)));
typedef float  f32x4  __attribute__((ext_vector_type(4)));
typedef unsigned short u16x8 __attribute__((ext_vector_type(8)));

#define TT    64
#define T_CTX 24
#define HOR   40
#define SA    264     // LDS row stride (K=256 + 8 pad): 528B, 16B-aligned
#define NTH   512     // 8 waves
#define EWS   132     // s_ew node stride (floats)

#define MFMA __builtin_amdgcn_mfma_f32_16x16x32_bf16

// ---- ws layout (bf16-element offsets; flag int at elem 0) ----
#define O_PKE   16                      // enc stream: 8 waves x 64 frags x 512
#define O_PKD   (O_PKE + 262144)        // dec stream: 8 x 72 x 512
#define O_PKX   (O_PKD + 294912)        // enc-term stream: 8 x 32 x 512
#define O_BIAS  (O_PKX + 131072)        // 4 x 512
#define O_HEADP (O_BIAS + 2048)         // h2in_b1|h2in_W2|h2out_b1|h2out_W2
#define O_WINE  (O_HEADP + 512)         // enc_W_in rows padded to 12
#define O_WINN  (O_WINE + 1536)
#define O_B2    (O_WINN + 1536)

struct Ptrs { const void* q[29]; };

__device__ __forceinline__ float sigm(float x) {
  return __builtin_amdgcn_rcpf(1.f + __expf(-x));
}
__device__ __forceinline__ float tanh_(float x) {
  return 1.f - 2.f * __builtin_amdgcn_rcpf(1.f + __expf(2.f * x));
}
__device__ __forceinline__ unsigned pk2(float a, float b) {
  unsigned ua = __float_as_uint(a), ub = __float_as_uint(b);
  ua = (ua + 0x7fffu + ((ua >> 16) & 1u)) >> 16;
  ub = (ub + 0x7fffu + ((ub >> 16) & 1u)) >> 16;
  return ua | (ub << 16);
}
__device__ __forceinline__ float uplo(unsigned p){ return __uint_as_float(p << 16); }
__device__ __forceinline__ float uphi(unsigned p){ return __uint_as_float(p & 0xffff0000u); }

// ================= dtype detector (unchanged, validated r2) =================
__global__ void detect_kernel(const unsigned short* __restrict__ wsrc, int* __restrict__ flag)
{
  int tid = threadIdx.x;
  int wild = 0;
  for (int i = tid; i < 256; i += 64) {
    unsigned short b = wsrc[i];
    float v  = __uint_as_float(((unsigned)b) << 16);
    float av = fabsf(v);
    unsigned e = (b >> 7) & 0xff;
    if (av > 1000.f || e == 0xff || (((b & 0x7fff) != 0) && av < 1e-9f)) wild++;
  }
  for (int off = 32; off; off >>= 1) wild += __shfl_down(wild, off, 64);
  if (tid == 0) flag[0] = (wild > 16) ? 1 : 0;
}

// ================= prep: pack weights into per-wave consumption-order streams =================
__global__ void prep_kernel(Ptrs P, bf16_t* __restrict__ wb, const int* __restrict__ flag)
{
  const bool f32 = (flag[0] != 0);
  const int gtid = blockIdx.x * blockDim.x + threadIdx.x;
  const int gsz  = gridDim.x * blockDim.x;
  auto rd = [&](const void* src, int i) -> float {
    return f32 ? ((const float*)src)[i] : (float)((const bf16_t*)src)[i];
  };

  // E stream: [w][seg(E0|E1)][kt][g] frags
  for (int i = gtid; i < 262144; i += gsz) {
    int w = i >> 15, r = i & 32767, f = r >> 9, e = r & 511;
    int ln = e >> 3, j = e & 7;
    int seg = f >> 5, fk = f & 31, kt = fk >> 2, g = fk & 3;
    int row = g * 128 + w * 16 + (ln & 15);
    int col = kt * 32 + ((ln >> 4) << 3) + j;
    float v;
    if (seg == 0) v = (col < 128) ? rd(P.q[4], row * 128 + col) : rd(P.q[5], row * 128 + col - 128);
    else          v = (col < 128) ? rd(P.q[8], row * 128 + col) : rd(P.q[9], row * 128 + col - 128);
    wb[O_PKE + i] = (bf16_t)v;
  }
  // D stream: [w][D0(32)|D1(32)|H(8)]
  for (int i = gtid; i < 294912; i += gsz) {
    int w = i / 36864, r = i - w * 36864, f = r >> 9, e = r & 511;
    int ln = e >> 3, j = e & 7;
    int colk = ((ln >> 4) << 3) + j;
    float v;
    if (f < 64) {
      int seg = f >> 5, fk = f & 31, kt = fk >> 2, g = fk & 3;
      int row = g * 128 + w * 16 + (ln & 15);
      int col = kt * 32 + colk;
      if (seg == 0) v = (col < 128) ? rd(P.q[13], row * 256 + col) : rd(P.q[14], row * 128 + col - 128);
      else          v = (col < 128) ? rd(P.q[17], row * 128 + col) : rd(P.q[18], row * 128 + col - 128);
    } else {
      int f2 = f - 64, h = f2 >> 2, kt = f2 & 3;
      int row = w * 16 + (ln & 15);
      int col = kt * 32 + colk;
      v = rd(h ? P.q[25] : P.q[21], row * 128 + col);
    }
    wb[O_PKD + i] = (bf16_t)v;
  }
  // X stream: inWih[:, 128:256]
  for (int i = gtid; i < 131072; i += gsz) {
    int w = i >> 14, r = i & 16383, f = r >> 9, e = r & 511;
    int ln = e >> 3, j = e & 7;
    int kt = f >> 2, g = f & 3;
    int row = g * 128 + w * 16 + (ln & 15);
    int col = kt * 32 + ((ln >> 4) << 3) + j;
    wb[O_PKX + i] = (bf16_t)rd(P.q[13], row * 256 + 128 + col);
  }
  // biases / head params / input-proj weights
  for (int i = gtid; i < 512; i += gsz) {
    wb[O_BIAS + i]        = (bf16_t)(rd(P.q[6],  i) + rd(P.q[7],  i));
    wb[O_BIAS + 512 + i]  = (bf16_t)(rd(P.q[10], i) + rd(P.q[11], i));
    wb[O_BIAS + 1024 + i] = (bf16_t)(rd(P.q[15], i) + rd(P.q[16], i));
    wb[O_BIAS + 1536 + i] = (bf16_t)(rd(P.q[19], i) + rd(P.q[20], i));
  }
  for (int i = gtid; i < 128; i += gsz) {
    wb[O_HEADP + i]       = (bf16_t)rd(P.q[22], i);
    wb[O_HEADP + 128 + i] = (bf16_t)rd(P.q[23], i);
    wb[O_HEADP + 256 + i] = (bf16_t)rd(P.q[26], i);
    wb[O_HEADP + 384 + i] = (bf16_t)rd(P.q[27], i);
  }
  for (int i = gtid; i < 1536; i += gsz) {
    int cc = i / 12, j = i % 12;
    wb[O_WINE + i] = (j < 10) ? (bf16_t)rd(P.q[3],  cc * 10 + j) : (bf16_t)0.f;
    wb[O_WINN + i] = (j < 10) ? (bf16_t)rd(P.q[12], cc * 10 + j) : (bf16_t)0.f;
  }
  if (gtid == 0) {
    wb[O_B2]     = (bf16_t)rd(P.q[24], 0);
    wb[O_B2 + 1] = (bf16_t)rd(P.q[28], 0);
  }
}

// ================= main-kernel building blocks =================
struct PreB { bf16x8 b[2][4]; };   // first 2 kt (8 frags) of a stream; 128B (SROA-safe)

__device__ __forceinline__ PreB preB(const bf16_t* __restrict__ pl) {
  PreB r;
#pragma unroll
  for (int p = 0; p < 2; ++p)
#pragma unroll
    for (int g = 0; g < 4; ++g)
      r.b[p][g] = *(const bf16x8*)(pl + (p * 4 + g) * 512);
  return r;
}

// acc[g][mt] += A[64, 32*NKT](LDS, stride SA) @ Wstream^T.
// Ring depth 4: kt0/kt1 via cross-barrier bundle (pre); bw[2],bw[3] issued at
// gemm start (2/3-kt cover); in-loop refills have 4-kt cover (~600cy). The
// NEXT phase's 2-kt bundle (pf) is issued at kt==1 so its latency hides under
// the remaining ~7 kt of this gemm + cell_up + barrier.
template<int NKT>
__device__ __forceinline__ void gemm_pk(f32x4 (&acc)[4][4], const bf16_t* __restrict__ As,
                                        const bf16_t* __restrict__ pl, const PreB& pre,
                                        const bf16_t* __restrict__ plpf, PreB* __restrict__ pf,
                                        int l, int q)
{
  bf16x8 bw[4][4];
#pragma unroll
  for (int g = 0; g < 4; ++g) { bw[0][g] = pre.b[0][g]; bw[1][g] = pre.b[1][g]; }
#pragma unroll
  for (int g = 0; g < 4; ++g) bw[2][g] = *(const bf16x8*)(pl + (8 + g) * 512);
  if (NKT > 3) {
#pragma unroll
    for (int g = 0; g < 4; ++g) bw[3][g] = *(const bf16x8*)(pl + (12 + g) * 512);
  }
#pragma unroll
  for (int kt = 0; kt < NKT; ++kt) {
    if (kt == 1) {
#pragma unroll
      for (int p = 0; p < 2; ++p)
#pragma unroll
        for (int g = 0; g < 4; ++g)
          pf->b[p][g] = *(const bf16x8*)(plpf + (p * 4 + g) * 512);
    }
    const bf16_t* Ar = As + l * SA + kt * 32 + q * 8;
    bf16x8 a0 = *(const bf16x8*)(Ar);
    bf16x8 a1 = *(const bf16x8*)(Ar + 16 * SA);
#pragma unroll
    for (int g = 0; g < 4; ++g) acc[g][0] = MFMA(a0, bw[kt % 4][g], acc[g][0], 0, 0, 0);
    a0 = *(const bf16x8*)(Ar + 32 * SA);
#pragma unroll
    for (int g = 0; g < 4; ++g) acc[g][1] = MFMA(a1, bw[kt % 4][g], acc[g][1], 0, 0, 0);
    a1 = *(const bf16x8*)(Ar + 48 * SA);
#pragma unroll
    for (int g = 0; g < 4; ++g) acc[g][2] = MFMA(a0, bw[kt % 4][g], acc[g][2], 0, 0, 0);
#pragma unroll
    for (int g = 0; g < 4; ++g) acc[g][3] = MFMA(a1, bw[kt % 4][g], acc[g][3], 0, 0, 0);
    // refill AFTER use: slot kt%4 just freed; data for kt+4 (lookahead 4)
    if (kt + 4 < NKT) {
#pragma unroll
      for (int g = 0; g < 4; ++g)
        bw[kt % 4][g] = *(const bf16x8*)(pl + ((kt + 4) * 4 + g) * 512);
    }
  }
}

// i,f,g,o for unit jc all in-lane (C layout: node=q*4+r within mt, unit=l). c in VGPRs.
template<bool DUAL>
__device__ __forceinline__ void cell_up(f32x4 (&acc)[4][4], float (&c)[16],
                                        bf16_t* __restrict__ shb, bf16_t* __restrict__ sha,
                                        const bf16_t* __restrict__ bias,
                                        int wid, int l, int q)
{
  const int jc = wid * 16 + l;
  const float bi  = (float)bias[jc];
  const float bf_ = (float)bias[128 + jc];
  const float bg  = (float)bias[256 + jc];
  const float bo  = (float)bias[384 + jc];
#pragma unroll
  for (int mt = 0; mt < 4; ++mt) {
#pragma unroll
    for (int r = 0; r < 4; ++r) {
      float gi = acc[0][mt][r] + bi;
      float gf = acc[1][mt][r] + bf_;
      float gg = acc[2][mt][r] + bg;
      float go = acc[3][mt][r] + bo;
      float cn = sigm(gf) * c[mt * 4 + r] + sigm(gi) * tanh_(gg);
      float hh = sigm(go) * tanh_(cn);
      c[mt * 4 + r] = cn;
      const int row = mt * 16 + q * 4 + r;
      shb[row * SA + jc] = (bf16_t)hh;
      if (DUAL) sha[row * SA + jc] = (bf16_t)hh;
    }
  }
}

__device__ __forceinline__ void proj16(const float* v, const bf16_t* __restrict__ wbase,
                                       bf16_t* __restrict__ sx, int nd, int sub)
{
  bf16x8 o0, o1;
#pragma unroll
  for (int cc = 0; cc < 16; ++cc) {
    const bf16_t* wr = wbase + (sub * 16 + cc) * 12;
    bf16x4 w0 = *(const bf16x4*)(wr);
    bf16x4 w1 = *(const bf16x4*)(wr + 4);
    bf16x4 w2 = *(const bf16x4*)(wr + 8);
    float a = v[0] * (float)w0[0] + v[1] * (float)w0[1] + v[2] * (float)w0[2] + v[3] * (float)w0[3]
            + v[4] * (float)w1[0] + v[5] * (float)w1[1] + v[6] * (float)w1[2] + v[7] * (float)w1[3]
            + v[8] * (float)w2[0] + v[9] * (float)w2[1];
    if (cc < 8) o0[cc] = (bf16_t)a; else o1[cc - 8] = (bf16_t)a;
  }
  *(bf16x8*)(sx + nd * SA + sub * 16)     = o0;
  *(bf16x8*)(sx + nd * SA + sub * 16 + 8) = o1;
}

// ================= persistent LSTM kernel =================
// amdgpu_waves_per_eu(2,2): LDS (122.6KB) pins us to 1 block/CU = 2 waves/EU
// regardless. launch_bounds' 2nd arg only RAISES the allocator's ceiling (R7:
// VGPR stayed 128, ring state spilled, WRITE_SIZE 2x). Pinning min=max=2 sets
// the allocator's TARGET to the occupancy we physically run at -> 256-VGPR
// budget -> ring-4 fits without scratch.
template<typename T>
__global__ __launch_bounds__(NTH)
__attribute__((amdgpu_waves_per_eu(2, 2)))
void lstm_persist(
    const T* __restrict__ x, const T* __restrict__ coords, const T* __restrict__ env,
    const bf16_t* __restrict__ w, const int* __restrict__ flag, T* __restrict__ out)
{
  const bool want_f32 = (sizeof(T) == 4);
  if ((flag[0] != 0) != want_f32) return;

  __shared__ __align__(16) bf16_t bufA[64 * SA];   // [inp | h0]
  __shared__ __align__(16) bf16_t bufB[64 * SA];   // [h0 | h1]
  __shared__ __align__(16) bf16_t s_win[2 * 128 * 12];
  __shared__ __align__(16) bf16_t s_bias[4 * 512];
  __shared__ float s_red[128];
  __shared__ float s_xc[64];
  __shared__ __align__(16) float s_ew[64 * EWS];   // 16-step window: [node][e0..6|x][16]
  __shared__ float s_out[64 * HOR];                // [node][s]

  const int tid  = threadIdx.x;
  const int wid  = tid >> 6;
  const int lane = tid & 63;
  const int l    = tid & 15;
  const int q    = (tid & 63) >> 4;
  const int node0 = blockIdx.x * 64;
  const int nd  = tid >> 3;
  const int sub = tid & 7;
  const int nd_e = tid / 7;            // env row indices (valid tid<448)
  const int e_e  = tid - nd_e * 7;

  const bf16_t* plE0 = w + O_PKE + wid * 32768 + lane * 8;
  const bf16_t* plE1 = plE0 + 16384;
  const bf16_t* plD0 = w + O_PKD + wid * 36864 + lane * 8;
  const bf16_t* plD1 = plD0 + 16384;
  const bf16_t* plH  = plD0 + 32768;
  const bf16_t* plX  = w + O_PKX + wid * 16384 + lane * 8;

  // env/x 16-step window loader (NT: single-touch per block)
  auto load_ew = [&](int t0) {
    float* dst = (tid < 448) ? &s_ew[nd_e * EWS + e_e * 16]
                             : &s_ew[(tid - 448) * EWS + 112];
    const T* src = (tid < 448) ? env + ((size_t)(node0 + nd_e) * 7 + e_e) * TT + t0
                               : x + (size_t)(node0 + tid - 448) * TT + t0;
    if constexpr (sizeof(T) == 4) {
#pragma unroll
      for (int u = 0; u < 4; ++u) {
        f32x4 vv = __builtin_nontemporal_load((const f32x4*)src + u);
        *((f32x4*)dst + u) = vv;
      }
    } else {
#pragma unroll
      for (int u = 0; u < 2; ++u) {
        u16x8 vv = __builtin_nontemporal_load((const u16x8*)src + u);
#pragma unroll
        for (int k = 0; k < 8; ++k)
          dst[u * 8 + k] = __uint_as_float(((unsigned)vv[k]) << 16);
      }
    }
  };

  for (int i = tid; i < 2048; i += NTH) s_bias[i] = w[O_BIAS + i];
  for (int i = tid; i < 3072; i += NTH) s_win[i]  = w[O_WINE + i];
  for (int i = tid; i < 64 * SA; i += NTH) { bufA[i] = (bf16_t)0.f; bufB[i] = (bf16_t)0.f; }
  load_ew(0);

  const float cx = (float)coords[(size_t)(node0 + nd) * 2 + 0];
  const float cy = (float)coords[(size_t)(node0 + nd) * 2 + 1];

  float c0[16], c1[16];
#pragma unroll
  for (int i = 0; i < 16; ++i) { c0[i] = 0.f; c1[i] = 0.f; }

  PreB pA = preB(plE0);
  PreB pD;
  __syncthreads();

  // ================= encoder =================
#pragma unroll 1
  for (int t = 0; t < T_CTX; ++t) {
    if (t == 16) { __syncthreads(); load_ew(16); __syncthreads(); }
    const int tw = t & 15;
    float v[10];
    v[0] = s_ew[nd * EWS + 112 + tw];
    v[1] = cx; v[2] = cy;
#pragma unroll
    for (int e = 0; e < 7; ++e) v[3 + e] = s_ew[nd * EWS + e * 16 + tw];
    proj16(v, s_win, bufA, nd, sub);
    __syncthreads();                           // E1: bufA ready

    f32x4 acc[4][4];
#pragma unroll
    for (int g = 0; g < 4; ++g)
#pragma unroll
      for (int mt = 0; mt < 4; ++mt) acc[g][mt] = f32x4{0.f, 0.f, 0.f, 0.f};
    PreB pC;
    gemm_pk<8>(acc, bufA, plE0, pA, plE1, &pC, l, q);
    __syncthreads();                           // E2: bufA consumed
    cell_up<true>(acc, c0, bufB, bufA + 128, s_bias, wid, l, q);
    __syncthreads();                           // E3: bufB[0:128] ready

#pragma unroll
    for (int g = 0; g < 4; ++g)
#pragma unroll
      for (int mt = 0; mt < 4; ++mt) acc[g][mt] = f32x4{0.f, 0.f, 0.f, 0.f};
    gemm_pk<8>(acc, bufB, plE1, pC, (t < T_CTX - 1) ? plE0 : plX, &pA, l, q);
    __syncthreads();                           // E4: bufB consumed
    cell_up<false>(acc, c1, bufB + 128, nullptr, s_bias + 512, wid, l, q);
  }
  __syncthreads();                             // enc-final h1 visible

  // ---- enc_state @ inWih[:,128:256]^T once, cached as bf16 (hi) ----
  uint2 geh[4][4];
  {
    f32x4 acc[4][4];
#pragma unroll
    for (int g = 0; g < 4; ++g)
#pragma unroll
      for (int mt = 0; mt < 4; ++mt) acc[g][mt] = f32x4{0.f, 0.f, 0.f, 0.f};
    gemm_pk<4>(acc, bufB + 128, plX, pA, plD0, &pD, l, q);   // prefetch pD here
#pragma unroll
    for (int g = 0; g < 4; ++g)
#pragma unroll
      for (int mt = 0; mt < 4; ++mt)
        geh[g][mt] = uint2{pk2(acc[g][mt][0], acc[g][mt][1]),
                           pk2(acc[g][mt][2], acc[g][mt][3])};
  }
  // x[:, T_CTX-1]: t=23 lives in resident window 1 (t16..31)
  if (tid < 64) s_xc[tid] = s_ew[tid * EWS + 112 + 7];
  const float b2i = (float)w[O_B2];
  const float b2o = (float)w[O_B2 + 1];
  const float b1i = (float)w[O_HEADP + wid * 16 + l];
  const float w2i = (float)w[O_HEADP + 128 + wid * 16 + l];
  const float b1o = (float)w[O_HEADP + 256 + wid * 16 + l];
  const float w2o = (float)w[O_HEADP + 384 + wid * 16 + l];
  __syncthreads();                             // s_xc ready

  // ================= decoder =================
#pragma unroll 1
  for (int s = 0; s < HOR; ++s) {
    const int t = T_CTX + s;
    if ((t & 15) == 0) { load_ew(t); __syncthreads(); }
    const int tw = t & 15;
    float v[10];
    v[0] = s_xc[nd];
    v[1] = cx; v[2] = cy;
#pragma unroll
    for (int e = 0; e < 7; ++e) v[3 + e] = s_ew[nd * EWS + e * 16 + tw];
    proj16(v, s_win + 1536, bufA, nd, sub);
    __syncthreads();                           // S1: bufA ready

    f32x4 acc[4][4];
#pragma unroll
    for (int g = 0; g < 4; ++g)
#pragma unroll
      for (int mt = 0; mt < 4; ++mt)
        acc[g][mt] = f32x4{uplo(geh[g][mt].x), uphi(geh[g][mt].x),
                           uplo(geh[g][mt].y), uphi(geh[g][mt].y)};
    PreB pC;
    gemm_pk<8>(acc, bufA, plD0, pD, plD1, &pC, l, q);
    __syncthreads();                           // S2: bufA consumed
    cell_up<true>(acc, c0, bufB, bufA + 128, s_bias + 1024, wid, l, q);
    __syncthreads();                           // S3: bufB[0:128] ready

#pragma unroll
    for (int g = 0; g < 4; ++g)
#pragma unroll
      for (int mt = 0; mt < 4; ++mt) acc[g][mt] = f32x4{0.f, 0.f, 0.f, 0.f};
    gemm_pk<8>(acc, bufB, plD1, pC, plD0, &pD, l, q);        // prefetch next-step pD
    bf16x8 hb[8];
#pragma unroll
    for (int f = 0; f < 8; ++f) hb[f] = *(const bf16x8*)(plH + f * 512);
    __syncthreads();                           // S4: bufB consumed
    cell_up<false>(acc, c1, bufB + 128, nullptr, s_bias + 1536, wid, l, q);
    if (tid < 128) s_red[tid] = 0.f;
    __syncthreads();                           // S5: h1 + s_red ready

    // ---- heads ----
    f32x4 hacc[2][4];
#pragma unroll
    for (int hd = 0; hd < 2; ++hd)
#pragma unroll
      for (int mt = 0; mt < 4; ++mt) hacc[hd][mt] = f32x4{0.f, 0.f, 0.f, 0.f};
#pragma unroll
    for (int kt = 0; kt < 4; ++kt) {
      bf16x8 a[4];
#pragma unroll
      for (int mt = 0; mt < 4; ++mt)
        a[mt] = *(const bf16x8*)(bufB + 128 + (mt * 16 + l) * SA + kt * 32 + q * 8);
#pragma unroll
      for (int mt = 0; mt < 4; ++mt) {
        hacc[0][mt] = MFMA(a[mt], hb[kt],     hacc[0][mt], 0, 0, 0);
        hacc[1][mt] = MFMA(a[mt], hb[4 + kt], hacc[1][mt], 0, 0, 0);
      }
    }
#pragma unroll
    for (int hd = 0; hd < 2; ++hd) {
      const float b1v = hd ? b1o : b1i;
      const float w2v = hd ? w2o : w2i;
#pragma unroll
      for (int mt = 0; mt < 4; ++mt)
#pragma unroll
        for (int r = 0; r < 4; ++r) {
          float val = fmaxf(hacc[hd][mt][r] + b1v, 0.f) * w2v;
          val += __shfl_xor(val, 1, 64);
          val += __shfl_xor(val, 2, 64);
          val += __shfl_xor(val, 4, 64);
          val += __shfl_xor(val, 8, 64);
          if (l == 0) atomicAdd(&s_red[hd * 64 + mt * 16 + q * 4 + r], val);
        }
    }
    __syncthreads();                           // S6: s_red complete
    if (tid < 64) {
      float xc = s_xc[tid];
      float si = sigm(s_red[tid] + b2i);
      float so = sigm(s_red[64 + tid] + b2o);
      float xn = xc + si - so * xc;
      s_xc[tid] = xn;
      s_out[tid * HOR + s] = xn;
    }
    __syncthreads();                           // S7: s_xc stable
  }

  // dump block outputs once, coalesced
  for (int i = tid; i < 64 * HOR; i += NTH)
    out[(size_t)node0 * HOR + i] = (T)s_out[i];
}

extern "C" void kernel_launch(void* const* d_in, const int* in_sizes, int n_in,
                              void* d_out, int out_size, void* d_ws, size_t ws_size,
                              hipStream_t stream) {
  (void)in_sizes; (void)n_in; (void)out_size; (void)ws_size;
  Ptrs P;
  for (int i = 0; i < 29; ++i) P.q[i] = d_in[i];
  int*    flag = (int*)d_ws;
  bf16_t* w    = (bf16_t*)d_ws;

  detect_kernel<<<1, 64, 0, stream>>>((const unsigned short*)d_in[4], flag);
  prep_kernel<<<256, 256, 0, stream>>>(P, w, flag);
  lstm_persist<float><<<256, NTH, 0, stream>>>(
      (const float*)d_in[0], (const float*)d_in[1], (const float*)d_in[2],
      w, flag, (float*)d_out);
  lstm_persist<bf16_t><<<256, NTH, 0, stream>>>(
      (const bf16_t*)d_in[0], (const bf16_t*)d_in[1], (const bf16_t*)d_in[2],
      w, flag, (bf16_t*)d_out);
}